// Round 8
// baseline (1891.644 us; speedup 1.0000x reference)
//
#include <hip/hip_runtime.h>
#include <math.h>

typedef float f4u __attribute__((ext_vector_type(4), aligned(4)));
typedef float nfloat4 __attribute__((ext_vector_type(4), aligned(16)));

__device__ __forceinline__ float softsign(float v) {
    float d = 1.0f + fabsf(v);
    return v * __builtin_amdgcn_rcpf(d);
}
__device__ __forceinline__ void nt_store4(float* p, float a, float b, float c, float d) {
    nfloat4 v; v.x = a; v.y = b; v.z = c; v.w = d;
    __builtin_nontemporal_store(v, (nfloat4*)p);
}
__device__ __forceinline__ int clamp63(int v) { return v < 0 ? 0 : (v > 63 ? 63 : v); }

__device__ __forceinline__ void load_row6(const float* __restrict__ row, int x0, float r[6]) {
    const float4 v = *(const float4*)(row + x0);
    r[0] = row[x0 == 0 ? 0 : x0 - 1];
    r[1] = v.x; r[2] = v.y; r[3] = v.z; r[4] = v.w;
    r[5] = row[x0 == 60 ? 63 : x0 + 4];
}

// -------- first layer: 2 input channels -> 1 channel --------
__global__ __launch_bounds__(256) void conv_first(const float* __restrict__ in0,
                                                  const float* __restrict__ in1,
                                                  float* __restrict__ out,
                                                  const float* __restrict__ w,
                                                  const float* __restrict__ bias) {
    int tid = blockIdx.x * 256 + threadIdx.x;
    int xq = (tid & 15) << 2;
    int y  = (tid >> 4) & 63;
    int z0 = ((tid >> 10) & 15) << 2;
    int b  = tid >> 14;
    const float* base0 = in0 + (size_t)b * 262144;
    const float* base1 = in1 + (size_t)b * 262144;

    float acc[4][4];
    #pragma unroll
    for (int i = 0; i < 4; ++i)
        #pragma unroll
        for (int j = 0; j < 4; ++j) acc[i][j] = 0.0f;

    #pragma unroll
    for (int zi = 0; zi < 6; ++zi) {
        int zin = clamp63(z0 + zi - 1);
        const float* p0 = base0 + zin * 4096;
        const float* p1 = base1 + zin * 4096;
        #pragma unroll
        for (int dy = 0; dy < 3; ++dy) {
            int yin = clamp63(y + dy - 1);
            float r0[6], r1[6];
            load_row6(p0 + yin * 64, xq, r0);
            load_row6(p1 + yin * 64, xq, r1);
            #pragma unroll
            for (int dz = 0; dz < 3; ++dz) {
                int zo = zi - dz;
                if (zo >= 0 && zo < 4) {
                    #pragma unroll
                    for (int dx = 0; dx < 3; ++dx) {
                        float w0v = w[dz * 9 + dy * 3 + dx];
                        float w1v = w[27 + dz * 9 + dy * 3 + dx];
                        #pragma unroll
                        for (int xx = 0; xx < 4; ++xx) {
                            acc[zo][xx] = fmaf(w0v, r0[xx + dx], acc[zo][xx]);
                            acc[zo][xx] = fmaf(w1v, r1[xx + dx], acc[zo][xx]);
                        }
                    }
                }
            }
        }
    }
    float bv = *bias;
    float* obase = out + (size_t)b * 262144 + (size_t)z0 * 4096 + y * 64 + xq;
    #pragma unroll
    for (int zo = 0; zo < 4; ++zo) {
        float4 o;
        o.x = softsign(acc[zo][0] + bv);
        o.y = softsign(acc[zo][1] + bv);
        o.z = softsign(acc[zo][2] + bv);
        o.w = softsign(acc[zo][3] + bv);
        *(float4*)(obase + zo * 4096) = o;
    }
}

// ============ fused pair of middle layers ============
// Block output tile: 64x * 8y * 4z.  Grid 2048 (16b * 8yt * 16zt).
// A: input, 8 planes (pa: in[clamp(z0-2+pa)]) x 12 rows (pr: in[clamp(y0-2+pr)]),
//    idx = x+2 (x in [-2,65], edge-clamped values), stride 72.  27.6 KB.
// B: intermediate, 6 planes (pb: inter[clamp(z0-1+pb)]) x 10 rows (rb: inter[clamp(y0-1+rb)]),
//    idx = x+1 (x in [-1,64], edge-dup values), stride 68.  16.3 KB.
// Edge-pad fusion: A/B store clamped/dup values; layer-1 evaluates at remapped (dup) rows
// for y, dups planes for z, dups lane-0 x; taps use identity index mapping pr=rb_eval+dy,
// pa=pb+dz which is exact because A's clamped storage supplies clamped taps.
#define AROW 72
#define APLANE 864    // 12*72
#define BROW 68
#define BPLANE 680    // 10*68

__global__ __launch_bounds__(256) void conv_mid2(const float* __restrict__ in,
                                                 float* __restrict__ out,
                                                 const float* __restrict__ w1p,
                                                 const float* __restrict__ b1p,
                                                 const float* __restrict__ w2p,
                                                 const float* __restrict__ b2p) {
    __shared__ float A[8 * APLANE];
    __shared__ float B[6 * BPLANE];

    int blk = blockIdx.x;
    int y0 = (blk & 7) << 3;           // 0..56
    int z0 = ((blk >> 3) & 15) << 2;   // 0..60
    int b  = blk >> 7;                 // 0..15
    int t  = threadIdx.x;
    int l  = t & 15;
    int g  = t >> 4;

    const float* base = in + (size_t)b * 262144;

    // ---- stage A: 96 rows = 6 iters x 16 g ----
    #pragma unroll
    for (int it = 0; it < 6; ++it) {
        int rid = it * 16 + g;          // 0..95
        int pa = rid / 12;
        int pr = rid - pa * 12;
        int gz = clamp63(z0 - 2 + pa);
        int gy = clamp63(y0 - 2 + pr);
        const float* grow = base + gz * 4096 + gy * 64;
        float* lrow = &A[pa * APLANE + pr * AROW];
        if (l == 0) {
            float2 v = *(const float2*)grow;                    // in[0], in[1]
            *(float4*)lrow = (float4){v.x, v.x, v.x, v.y};      // x=-2,-1,0,1
        } else {
            f4u v = *(const f4u*)(grow + 4 * l - 2);            // x = 4l-2..4l+1
            *(float4*)(lrow + 4 * l) = (float4){v.x, v.y, v.z, v.w};
        }
        if (l == 15) {
            float2 v = *(const float2*)(grow + 62);             // in[62], in[63]
            *(float4*)(lrow + 64) = (float4){v.x, v.y, v.y, v.y}; // x=62,63,64d,65d
        }
    }

    float w1[27];
    #pragma unroll
    for (int i = 0; i < 27; ++i) w1[i] = w1p[i];
    float b1 = *b1p;

    __syncthreads();

    // ---- layer 1: fill B ----
    if (g < 10) {
        int rb = g;
        int rb_eval = rb;
        if (y0 == 0 && rb == 0) rb_eval = 1;
        if (y0 == 56 && rb == 9) rb_eval = 8;

        float acc6[6][4];
        #pragma unroll
        for (int p = 0; p < 6; ++p)
            #pragma unroll
            for (int k = 0; k < 4; ++k) acc6[p][k] = 0.0f;

        #pragma unroll
        for (int pa = 0; pa < 8; ++pa) {
            float r[3][6];
            #pragma unroll
            for (int dy = 0; dy < 3; ++dy) {
                const float* ar = &A[pa * APLANE + (rb_eval + dy) * AROW + 4 * l];
                float4 u  = *(const float4*)ar;
                float2 u2 = *(const float2*)(ar + 4);
                r[dy][0] = u.x; r[dy][1] = u.y; r[dy][2] = u.z;
                r[dy][3] = u.w; r[dy][4] = u2.x; r[dy][5] = u2.y;
            }
            #pragma unroll
            for (int dz = 0; dz < 3; ++dz) {
                int pb = pa - dz;
                if (pb >= 0 && pb < 6) {
                    #pragma unroll
                    for (int dy = 0; dy < 3; ++dy)
                        #pragma unroll
                        for (int dx = 0; dx < 3; ++dx) {
                            float wv = w1[dz * 9 + dy * 3 + dx];
                            #pragma unroll
                            for (int k = 0; k < 4; ++k)
                                acc6[pb][k] = fmaf(wv, r[dy][k + dx], acc6[pb][k]);
                        }
                }
            }
        }

        float vals[6][4];
        #pragma unroll
        for (int p = 0; p < 6; ++p)
            #pragma unroll
            for (int k = 0; k < 4; ++k) vals[p][k] = softsign(acc6[p][k] + b1);

        if (l == 0) {
            #pragma unroll
            for (int p = 0; p < 6; ++p) vals[p][0] = vals[p][1];   // x=-1 dup of x=0
        }
        if (z0 == 0) {
            #pragma unroll
            for (int k = 0; k < 4; ++k) vals[0][k] = vals[1][k];   // z-dup low
        }
        if (z0 == 60) {
            #pragma unroll
            for (int k = 0; k < 4; ++k) vals[5][k] = vals[4][k];   // z-dup high
        }
        #pragma unroll
        for (int p = 0; p < 6; ++p) {
            *(float4*)(&B[p * BPLANE + rb * BROW + 4 * l]) =
                (float4){vals[p][0], vals[p][1], vals[p][2], vals[p][3]};
        }
    } else if (g == 10 && l < 10) {
        // x-tail: inter(x=63) for row rb=l, all 6 planes; writes idx 64 (x=63) + 65 (dup)
        int rb = l;
        int rb_eval = rb;
        if (y0 == 0 && rb == 0) rb_eval = 1;
        if (y0 == 56 && rb == 9) rb_eval = 8;

        float acc6[6];
        #pragma unroll
        for (int p = 0; p < 6; ++p) acc6[p] = 0.0f;

        #pragma unroll
        for (int pa = 0; pa < 8; ++pa) {
            float rr[3][3];
            #pragma unroll
            for (int dy = 0; dy < 3; ++dy) {
                const float* ar = &A[pa * APLANE + (rb_eval + dy) * AROW + 64];
                float2 u = *(const float2*)ar;                     // x=62,63
                rr[dy][0] = u.x; rr[dy][1] = u.y; rr[dy][2] = ar[2]; // x=64 dup
            }
            #pragma unroll
            for (int dz = 0; dz < 3; ++dz) {
                int pb = pa - dz;
                if (pb >= 0 && pb < 6) {
                    #pragma unroll
                    for (int dy = 0; dy < 3; ++dy)
                        #pragma unroll
                        for (int dx = 0; dx < 3; ++dx)
                            acc6[pb] = fmaf(w1[dz * 9 + dy * 3 + dx], rr[dy][dx], acc6[pb]);
                }
            }
        }
        float vals[6];
        #pragma unroll
        for (int p = 0; p < 6; ++p) vals[p] = softsign(acc6[p] + b1);
        if (z0 == 0)  vals[0] = vals[1];
        if (z0 == 60) vals[5] = vals[4];
        #pragma unroll
        for (int p = 0; p < 6; ++p)
            *(float2*)(&B[p * BPLANE + rb * BROW + 64]) = (float2){vals[p], vals[p]};
    }

    float w2[27];
    #pragma unroll
    for (int i = 0; i < 27; ++i) w2[i] = w2p[i];
    float b2 = *b2p;

    __syncthreads();

    // ---- layer 2: thread = 4x * 1y * 2z ----
    int yloc = g & 7;
    int zh   = g >> 3;     // output z = z0 + 2*zh + {0,1}

    float acc[2][4];
    #pragma unroll
    for (int i = 0; i < 2; ++i)
        #pragma unroll
        for (int j = 0; j < 4; ++j) acc[i][j] = 0.0f;

    #pragma unroll
    for (int pz = 0; pz < 4; ++pz) {
        const float* pl = &B[(2 * zh + pz) * BPLANE];
        #pragma unroll
        for (int dy = 0; dy < 3; ++dy) {
            const float* br = pl + (yloc + dy) * BROW + 4 * l;
            float4 u  = *(const float4*)br;
            float2 u2 = *(const float2*)(br + 4);
            float r[6] = {u.x, u.y, u.z, u.w, u2.x, u2.y};
            #pragma unroll
            for (int dz = 0; dz < 3; ++dz) {
                int zo = pz - dz;
                if (zo >= 0 && zo < 2) {
                    #pragma unroll
                    for (int dx = 0; dx < 3; ++dx) {
                        float wv = w2[dz * 9 + dy * 3 + dx];
                        #pragma unroll
                        for (int k = 0; k < 4; ++k)
                            acc[zo][k] = fmaf(wv, r[k + dx], acc[zo][k]);
                    }
                }
            }
        }
    }

    int y = y0 + yloc;
    float* obase = out + (size_t)b * 262144 + (size_t)(z0 + 2 * zh) * 4096 + y * 64 + 4 * l;
    #pragma unroll
    for (int zo = 0; zo < 2; ++zo) {
        float4 o;
        o.x = softsign(acc[zo][0] + b2);
        o.y = softsign(acc[zo][1] + b2);
        o.z = softsign(acc[zo][2] + b2);
        o.w = softsign(acc[zo][3] + b2);
        *(float4*)(obase + zo * 4096) = o;
    }
}

// -------- last layer: 1 -> 3 channels + strided downsample outputs --------
__global__ __launch_bounds__(256) void conv_last(const float* __restrict__ in,
                                                 float* __restrict__ out,
                                                 const float* __restrict__ w,
                                                 const float* __restrict__ bias) {
    int tid = blockIdx.x * 256 + threadIdx.x;
    int xq = (tid & 15) << 2;
    int y  = (tid >> 4) & 63;
    int z0 = ((tid >> 10) & 15) << 2;
    int b  = tid >> 14;
    const float* base = in + (size_t)b * 262144;

    float acc[4][3][4];
    #pragma unroll
    for (int i = 0; i < 4; ++i)
        #pragma unroll
        for (int c = 0; c < 3; ++c)
            #pragma unroll
            for (int j = 0; j < 4; ++j) acc[i][c][j] = 0.0f;

    #pragma unroll
    for (int zi = 0; zi < 6; ++zi) {
        int zin = clamp63(z0 + zi - 1);
        const float* plane = base + zin * 4096;
        #pragma unroll
        for (int dy = 0; dy < 3; ++dy) {
            int yin = clamp63(y + dy - 1);
            float r[6];
            load_row6(plane + yin * 64, xq, r);
            #pragma unroll
            for (int dz = 0; dz < 3; ++dz) {
                int zo = zi - dz;
                if (zo >= 0 && zo < 4) {
                    #pragma unroll
                    for (int c = 0; c < 3; ++c) {
                        #pragma unroll
                        for (int dx = 0; dx < 3; ++dx) {
                            float wc = w[c * 27 + dz * 9 + dy * 3 + dx];
                            #pragma unroll
                            for (int xx = 0; xx < 4; ++xx)
                                acc[zo][c][xx] = fmaf(wc, r[xx + dx], acc[zo][c][xx]);
                        }
                    }
                }
            }
        }
    }

    float* r64 = out;
    float* r32 = out + 12582912;
    float* r16 = r32 + 1572864;
    float* r8  = r16 + 196608;

    float vals[4][3][4];
    #pragma unroll
    for (int zo = 0; zo < 4; ++zo)
        #pragma unroll
        for (int c = 0; c < 3; ++c) {
            float bv = bias[c];
            #pragma unroll
            for (int xx = 0; xx < 4; ++xx)
                vals[zo][c][xx] = softsign(acc[zo][c][xx] + bv);
        }

    #pragma unroll
    for (int c = 0; c < 3; ++c) {
        float* cb = r64 + ((size_t)b * 3 + c) * 262144 + (size_t)z0 * 4096 + y * 64 + xq;
        #pragma unroll
        for (int zo = 0; zo < 4; ++zo) {
            nt_store4(cb + zo * 4096,
                      vals[zo][c][0], vals[zo][c][1], vals[zo][c][2], vals[zo][c][3]);
        }
    }
    if ((y & 1) == 0) {
        #pragma unroll
        for (int c = 0; c < 3; ++c) {
            size_t cb = ((size_t)b * 3 + c) * 32768 + (size_t)(y >> 1) * 32;
            #pragma unroll
            for (int zo = 0; zo < 4; zo += 2) {
                size_t zb = cb + (size_t)((z0 + zo) >> 1) * 1024;
                __builtin_nontemporal_store(vals[zo][c][0], r32 + zb + ((xq + 0) >> 1));
                __builtin_nontemporal_store(vals[zo][c][2], r32 + zb + ((xq + 2) >> 1));
            }
        }
    }
    if ((y & 3) == 0) {
        #pragma unroll
        for (int c = 0; c < 3; ++c) {
            __builtin_nontemporal_store(vals[0][c][0],
                r16 + ((size_t)b * 3 + c) * 4096 + (size_t)(z0 >> 2) * 256 + (y >> 2) * 16 + (xq >> 2));
        }
    }
    if ((y & 7) == 0 && (z0 & 7) == 0 && (xq & 7) == 0) {
        #pragma unroll
        for (int c = 0; c < 3; ++c) {
            __builtin_nontemporal_store(vals[0][c][0],
                r8 + ((size_t)b * 3 + c) * 512 + (size_t)(z0 >> 3) * 64 + (y >> 3) * 8 + (xq >> 3));
        }
    }
}

extern "C" void kernel_launch(void* const* d_in, const int* in_sizes, int n_in,
                              void* d_out, int out_size, void* d_ws, size_t ws_size,
                              hipStream_t stream) {
    const float* preop = (const float*)d_in[0];
    const float* intra = (const float*)d_in[1];
    const float* w0    = (const float*)d_in[2];
    const float* b0    = (const float*)d_in[3];
    const float* ws    = (const float*)d_in[4];
    const float* bs    = (const float*)d_in[5];
    const float* wX    = (const float*)d_in[6];
    const float* bX    = (const float*)d_in[7];
    float* out = (float*)d_out;

    float* buf0 = (float*)d_ws;
    float* buf1 = out;

    conv_first<<<dim3(1024), dim3(256), 0, stream>>>(preop, intra, buf0, w0, b0);
    for (int k = 0; k < 50; ++k) {
        const float* src = (k & 1) ? buf1 : buf0;
        float* dst       = (k & 1) ? buf0 : buf1;
        conv_mid2<<<dim3(2048), dim3(256), 0, stream>>>(src, dst,
                                                        ws + (2 * k) * 27, bs + 2 * k,
                                                        ws + (2 * k + 1) * 27, bs + 2 * k + 1);
    }
    // k=49 (odd) wrote buf0 -> final layer reads buf0
    conv_last<<<dim3(1024), dim3(256), 0, stream>>>(buf0, out, wX, bX);
}